// Round 3
// baseline (551.667 us; speedup 1.0000x reference)
//
#include <hip/hip_runtime.h>
#include <stdint.h>

// ---------------------------------------------------------------------------
// torch-ngp hashgrid encode (16 levels, dim 2) + 32->64->8 ReLU MLP, 8-corner
// trilinear blend.  One thread per (point, outer corner); 8 threads/point are
// consecutive lanes -> shuffle reduction + coalesced store.
//
// R3 change vs R2 (335us, VALUBusy 71%, Occ 61%, VGPR 40):
//  * __launch_bounds__(256,8): R2's (256,6) cap was the occupancy binder
//    (VGPR only 40 of the 85 budget).  8 blocks/CU = 32 waves/CU covers the
//    remaining ~100us of exposed gather latency.  VGPR cap 64 >> 40 used.
//  Arithmetic bit-identical to the passing R2 kernel.
// ---------------------------------------------------------------------------

#define BLK 256

// Finest level resolution: ceil(16 * scale^15), 16*scale^15 == 513.0 +- ~1e-12
// in float64.  513 is the intended value (DESIRED_RES).
#define R15 513

// Linear (tight-grid) level: compile-time R/H/O so % H becomes magic-multiply.
template <int R, int H, int O>
__device__ __forceinline__ void enc_linear(float xcx, float xcy, float xcz,
                                           const float2* __restrict__ tab,
                                           float& f0, float& f1) {
    const float Rf = (float)R;
    // replicate reference op order: pos = x*R + 0.5 (no fma contraction)
    float px = __fadd_rn(__fmul_rn(xcx, Rf), 0.5f);
    float py = __fadd_rn(__fmul_rn(xcy, Rf), 0.5f);
    float pz = __fadd_rn(__fmul_rn(xcz, Rf), 0.5f);
    float fpx = floorf(px), fpy = floorf(py), fpz = floorf(pz);
    float frx = px - fpx, fry = py - fpy, frz = pz - fpz;
    int gx = (int)fpx, gy = (int)fpy, gz = (int)fpz;
    float wx[2] = {1.f - frx, frx};
    float wy[2] = {1.f - fry, fry};
    float wz[2] = {1.f - frz, frz};
    // hand-CSE the index terms (integer-exact, identical results)
    const int R1 = R + 1;
    int xt[2] = {gx, gx + 1};
    int yt[2] = {gy * R1, gy * R1 + R1};
    int zt[2] = {gz * R1 * R1, gz * R1 * R1 + R1 * R1};
    float a0 = 0.f, a1 = 0.f;
#pragma unroll
    for (int c = 0; c < 8; ++c) {  // corner order (x,y,z) = bits (2,1,0): matches CORNERS
        const int ox = (c >> 2) & 1, oy = (c >> 1) & 1, oz = c & 1;
        int id  = xt[ox] + yt[oy] + zt[oz];
        int idx = (int)((uint32_t)id % (uint32_t)H);  // reference applies % H even on tight grids
        float w = wx[ox] * wy[oy] * wz[oz];
        float2 tv = tab[O + idx];
        a0 = fmaf(w, tv.x, a0);
        a1 = fmaf(w, tv.y, a1);
    }
    f0 = a0; f1 = a1;
}

// Hashed level (H = 2^19): compile-time R/O, hand-CSE'd hash terms.
template <int RI, int O>
__device__ __forceinline__ void enc_hash(float xcx, float xcy, float xcz,
                                         const float2* __restrict__ tab,
                                         float& f0, float& f1) {
    const float Rf = (float)RI;
    float px = __fadd_rn(__fmul_rn(xcx, Rf), 0.5f);
    float py = __fadd_rn(__fmul_rn(xcy, Rf), 0.5f);
    float pz = __fadd_rn(__fmul_rn(xcz, Rf), 0.5f);
    float fpx = floorf(px), fpy = floorf(py), fpz = floorf(pz);
    float frx = px - fpx, fry = py - fpy, frz = pz - fpz;
    uint32_t gx = (uint32_t)(int)fpx, gy = (uint32_t)(int)fpy, gz = (uint32_t)(int)fpz;
    float wx[2] = {1.f - frx, frx};
    float wy[2] = {1.f - fry, fry};
    float wz[2] = {1.f - frz, frz};
    // instant-NGP fast_hash primes {1, 2654435761, 805459861}; CSE the 8 muls
    uint32_t xt[2] = {gx, gx + 1u};
    uint32_t yt[2] = {gy * 2654435761u, gy * 2654435761u + 2654435761u};
    uint32_t zt[2] = {gz * 805459861u,  gz * 805459861u  + 805459861u};
    float a0 = 0.f, a1 = 0.f;
#pragma unroll
    for (int c = 0; c < 8; ++c) {
        const int ox = (c >> 2) & 1, oy = (c >> 1) & 1, oz = c & 1;
        uint32_t idx = (xt[ox] ^ yt[oy] ^ zt[oz]) & 524287u;
        float w = wx[ox] * wy[oy] * wz[oz];
        float2 tv = tab[O + (int)idx];
        a0 = fmaf(w, tv.x, a0);
        a1 = fmaf(w, tv.y, a1);
    }
    f0 = a0; f1 = a1;
}

__global__ __launch_bounds__(BLK, 8)
void grid_fused(const float* __restrict__ xyz, const float* __restrict__ bound,
                const float* __restrict__ table, const float* __restrict__ w1,
                const float* __restrict__ w2, float* __restrict__ out, int N) {
    const int tid = threadIdx.x;
    const int t = blockIdx.x * BLK + tid;
    const int p = t >> 3;
    const int a = t & 7;
    if (p >= N) return;

    const float2* tab = (const float2*)table;

    const float b = bound[0];
    float X = xyz[3 * p + 0], Y = xyz[3 * p + 1], Z = xyz[3 * p + 2];
    // x = (xyz + bound) / (2*bound); coords = x * 512
    float cx = ((X + b) / (2.0f * b)) * 512.0f;
    float cy = ((Y + b) / (2.0f * b)) * 512.0f;
    float cz = ((Z + b) / (2.0f * b)) * 512.0f;
    float c0x = fmaxf(fminf(floorf(cx), 511.f), 0.f);
    float c0y = fmaxf(fminf(floorf(cy), 511.f), 0.f);
    float c0z = fmaxf(fminf(floorf(cz), 511.f), 0.f);
    float uu = cx - c0x, vv = cy - c0y, wwf = cz - c0z;  // outer trilinear fracs

    const int ax = (a >> 2) & 1, ay = (a >> 1) & 1, az = a & 1;  // CORNERS order
    // encode-space coordinate of this outer corner: (c0+a)/512, exact
    float xcx = (c0x + (float)ax) * (1.0f / 512.0f);
    float xcy = (c0y + (float)ay) * (1.0f / 512.0f);
    float xcz = (c0z + (float)az) * (1.0f / 512.0f);

    // ---- all 16 levels -> 32 feature registers -----------------------------
    float fr[32];
    enc_linear<16,   4920,      0>(xcx, xcy, xcz, tab, fr[ 0], fr[ 1]);
    enc_linear<21,  10648,   4920>(xcx, xcy, xcz, tab, fr[ 2], fr[ 3]);
    enc_linear<26,  19688,  15568>(xcx, xcy, xcz, tab, fr[ 4], fr[ 5]);
    enc_linear<33,  39304,  35256>(xcx, xcy, xcz, tab, fr[ 6], fr[ 7]);
    enc_linear<41,  74088,  74560>(xcx, xcy, xcz, tab, fr[ 8], fr[ 9]);
    enc_linear<51, 140608, 148648>(xcx, xcy, xcz, tab, fr[10], fr[11]);
    enc_linear<65, 287496, 289256>(xcx, xcy, xcz, tab, fr[12], fr[13]);
    enc_hash< 81,  576752>(xcx, xcy, xcz, tab, fr[14], fr[15]);
    enc_hash<102, 1101040>(xcx, xcy, xcz, tab, fr[16], fr[17]);
    enc_hash<129, 1625328>(xcx, xcy, xcz, tab, fr[18], fr[19]);
    enc_hash<162, 2149616>(xcx, xcy, xcz, tab, fr[20], fr[21]);
    enc_hash<204, 2673904>(xcx, xcy, xcz, tab, fr[22], fr[23]);
    enc_hash<257, 3198192>(xcx, xcy, xcz, tab, fr[24], fr[25]);
    enc_hash<324, 3722480>(xcx, xcy, xcz, tab, fr[26], fr[27]);
    enc_hash<408, 4246768>(xcx, xcy, xcz, tab, fr[28], fr[29]);
    enc_hash<R15, 4771056>(xcx, xcy, xcz, tab, fr[30], fr[31]);

    // ---- MLP: relu(feats @ w1) @ w2, hidden dim in four 16-reg chunks ------
    // fr[] fully register-resident: i-loop is fully unrolled so every index
    // is compile-time (rule: runtime-indexed arrays go to scratch).
    // w1/w2 row pointers are wave-uniform -> s_load; FMA is v_fmac(v,s,v).
    // Accumulation order identical to R2 (hidden units ascending 0..63).
    float acc[8] = {0.f, 0.f, 0.f, 0.f, 0.f, 0.f, 0.f, 0.f};
#pragma unroll 1
    for (int kb = 0; kb < 64; kb += 16) {
        float h[16];
#pragma unroll
        for (int k = 0; k < 16; ++k) h[k] = 0.f;
#pragma unroll
        for (int i = 0; i < 32; ++i) {
            const float* wr = w1 + i * 64 + kb;  // wave-uniform -> s_load
#pragma unroll
            for (int k = 0; k < 16; ++k) h[k] = fmaf(fr[i], wr[k], h[k]);
        }
#pragma unroll
        for (int k = 0; k < 16; ++k) {
            float hk = fmaxf(h[k], 0.f);
            const float* w2r = w2 + (kb + k) * 8;  // wave-uniform -> s_load
#pragma unroll
            for (int j = 0; j < 8; ++j) acc[j] = fmaf(hk, w2r[j], acc[j]);
        }
    }

    // ---- outer trilinear weight + 8-lane reduction --------------------------
    float wt = (ax ? uu : 1.f - uu) * (ay ? vv : 1.f - vv) * (az ? wwf : 1.f - wwf);
#pragma unroll
    for (int j = 0; j < 8; ++j) {
        float v = acc[j] * wt;
        v += __shfl_xor(v, 1);
        v += __shfl_xor(v, 2);
        v += __shfl_xor(v, 4);
        acc[j] = v;  // all 8 lanes now hold the full sum for output j
    }
    // lane a writes output column a -> out[p*8 + a] == out[t], fully coalesced
    float r01 = (a & 1) ? acc[1] : acc[0];
    float r23 = (a & 1) ? acc[3] : acc[2];
    float r45 = (a & 1) ? acc[5] : acc[4];
    float r67 = (a & 1) ? acc[7] : acc[6];
    float r03 = (a & 2) ? r23 : r01;
    float r47 = (a & 2) ? r67 : r45;
    float r   = (a & 4) ? r47 : r03;
    out[t] = r;
}

extern "C" void kernel_launch(void* const* d_in, const int* in_sizes, int n_in,
                              void* d_out, int out_size, void* d_ws, size_t ws_size,
                              hipStream_t stream) {
    const float* xyz   = (const float*)d_in[0];
    const float* bound = (const float*)d_in[1];
    const float* table = (const float*)d_in[2];
    const float* w1    = (const float*)d_in[3];
    const float* w2    = (const float*)d_in[4];
    float* out = (float*)d_out;

    const int N = in_sizes[0] / 3;          // 262144
    const int threads = N * 8;              // one thread per (point, corner)
    const int blocks = (threads + BLK - 1) / BLK;
    grid_fused<<<blocks, BLK, 0, stream>>>(xyz, bound, table, w1, w2, out, N);
}

// Round 4
// 434.310 us; speedup vs baseline: 1.2702x; 1.2702x over previous
//
#include <hip/hip_runtime.h>
#include <stdint.h>

// ---------------------------------------------------------------------------
// torch-ngp hashgrid encode (16 levels, dim 2) + 32->64->8 ReLU MLP, 8-corner
// trilinear blend.  One thread per (point, outer corner); 8 threads/point are
// consecutive lanes -> shuffle reduction + coalesced store.
//
// R4 changes vs R2 (335us, VALUBusy 71%, MfmaUtil 0):
//  * MLP moved to the idle matrix pipe: per wave the MLP is a
//    64x32 @ 32x64 -> relu -> @ 64x8 GEMM.  mfma_f32_16x16x32_bf16 with
//    3-term split-bf16 (hi+lo, drop lo*lo): rel err ~2^-16, ~1e-5 abs.
//  * feats staged via 8 KB/wave LDS (reused for H halves, then O); all
//    intra-wave, no barriers (same-wave DS ordering + explicit lgkmcnt(0)).
//  * launch_bounds(256,4): VGPR cap 128 (R3's (256,8) caused scratch spills:
//    WRITE_SIZE 8->48 MB.  Tripwire: WRITE_SIZE must be 8192 KB).
//  Encode arithmetic bit-identical to the passing R2 kernel.
// ---------------------------------------------------------------------------

#define BLK 256
#define R15 513

typedef short short8 __attribute__((ext_vector_type(8)));
typedef short short4v __attribute__((ext_vector_type(4)));
typedef float f32x4 __attribute__((ext_vector_type(4)));

__device__ __forceinline__ short bf16_hi(float x) {
    return (short)(__float_as_uint(x) >> 16);           // truncation split
}
__device__ __forceinline__ float bf16_back(short h) {
    return __uint_as_float(((uint32_t)(uint16_t)h) << 16);  // exact
}

// Linear (tight-grid) level: compile-time R/H/O so % H becomes magic-multiply.
template <int R, int H, int O>
__device__ __forceinline__ void enc_linear(float xcx, float xcy, float xcz,
                                           const float2* __restrict__ tab,
                                           float& f0, float& f1) {
    const float Rf = (float)R;
    float px = __fadd_rn(__fmul_rn(xcx, Rf), 0.5f);
    float py = __fadd_rn(__fmul_rn(xcy, Rf), 0.5f);
    float pz = __fadd_rn(__fmul_rn(xcz, Rf), 0.5f);
    float fpx = floorf(px), fpy = floorf(py), fpz = floorf(pz);
    float frx = px - fpx, fry = py - fpy, frz = pz - fpz;
    int gx = (int)fpx, gy = (int)fpy, gz = (int)fpz;
    float wx[2] = {1.f - frx, frx};
    float wy[2] = {1.f - fry, fry};
    float wz[2] = {1.f - frz, frz};
    const int R1 = R + 1;
    int xt[2] = {gx, gx + 1};
    int yt[2] = {gy * R1, gy * R1 + R1};
    int zt[2] = {gz * R1 * R1, gz * R1 * R1 + R1 * R1};
    float a0 = 0.f, a1 = 0.f;
#pragma unroll
    for (int c = 0; c < 8; ++c) {
        const int ox = (c >> 2) & 1, oy = (c >> 1) & 1, oz = c & 1;
        int id  = xt[ox] + yt[oy] + zt[oz];
        int idx = (int)((uint32_t)id % (uint32_t)H);
        float w = wx[ox] * wy[oy] * wz[oz];
        float2 tv = tab[O + idx];
        a0 = fmaf(w, tv.x, a0);
        a1 = fmaf(w, tv.y, a1);
    }
    f0 = a0; f1 = a1;
}

// Hashed level (H = 2^19): compile-time R/O, hand-CSE'd hash terms.
template <int RI, int O>
__device__ __forceinline__ void enc_hash(float xcx, float xcy, float xcz,
                                         const float2* __restrict__ tab,
                                         float& f0, float& f1) {
    const float Rf = (float)RI;
    float px = __fadd_rn(__fmul_rn(xcx, Rf), 0.5f);
    float py = __fadd_rn(__fmul_rn(xcy, Rf), 0.5f);
    float pz = __fadd_rn(__fmul_rn(xcz, Rf), 0.5f);
    float fpx = floorf(px), fpy = floorf(py), fpz = floorf(pz);
    float frx = px - fpx, fry = py - fpy, frz = pz - fpz;
    uint32_t gx = (uint32_t)(int)fpx, gy = (uint32_t)(int)fpy, gz = (uint32_t)(int)fpz;
    float wx[2] = {1.f - frx, frx};
    float wy[2] = {1.f - fry, fry};
    float wz[2] = {1.f - frz, frz};
    uint32_t xt[2] = {gx, gx + 1u};
    uint32_t yt[2] = {gy * 2654435761u, gy * 2654435761u + 2654435761u};
    uint32_t zt[2] = {gz * 805459861u,  gz * 805459861u  + 805459861u};
    float a0 = 0.f, a1 = 0.f;
#pragma unroll
    for (int c = 0; c < 8; ++c) {
        const int ox = (c >> 2) & 1, oy = (c >> 1) & 1, oz = c & 1;
        uint32_t idx = (xt[ox] ^ yt[oy] ^ zt[oz]) & 524287u;
        float w = wx[ox] * wy[oy] * wz[oz];
        float2 tv = tab[O + (int)idx];
        a0 = fmaf(w, tv.x, a0);
        a1 = fmaf(w, tv.y, a1);
    }
    f0 = a0; f1 = a1;
}

__global__ __launch_bounds__(BLK, 4)
void grid_fused(const float* __restrict__ xyz, const float* __restrict__ bound,
                const float* __restrict__ table, const float* __restrict__ w1,
                const float* __restrict__ w2, float* __restrict__ out, int N) {
    // per-wave 8 KB scratch: F bf16 hi/lo planes -> H halves -> O fp32
    __shared__ __align__(16) char smem_raw[4 * 8192];

    const int tid = threadIdx.x;
    const int t = blockIdx.x * BLK + tid;
    const int p = t >> 3;
    const int a = t & 7;
    if (p >= N) return;

    const int wid  = tid >> 6;
    const int lane = tid & 63;
    const int q    = lane >> 4;   // 16-lane group (k-group for MFMA frags)
    const int cc   = lane & 15;   // within-group index (M/N index)
    char* wb = smem_raw + wid * 8192;

    const float2* tab = (const float2*)table;

    const float b = bound[0];
    float X = xyz[3 * p + 0], Y = xyz[3 * p + 1], Z = xyz[3 * p + 2];
    float cx = ((X + b) / (2.0f * b)) * 512.0f;
    float cy = ((Y + b) / (2.0f * b)) * 512.0f;
    float cz = ((Z + b) / (2.0f * b)) * 512.0f;
    float c0x = fmaxf(fminf(floorf(cx), 511.f), 0.f);
    float c0y = fmaxf(fminf(floorf(cy), 511.f), 0.f);
    float c0z = fmaxf(fminf(floorf(cz), 511.f), 0.f);
    float uu = cx - c0x, vv = cy - c0y, wwf = cz - c0z;

    const int ax = (a >> 2) & 1, ay = (a >> 1) & 1, az = a & 1;
    float xcx = (c0x + (float)ax) * (1.0f / 512.0f);
    float xcy = (c0y + (float)ay) * (1.0f / 512.0f);
    float xcz = (c0z + (float)az) * (1.0f / 512.0f);

    // ---- all 16 levels -> 32 feature registers (unchanged) -----------------
    float fr[32];
    enc_linear<16,   4920,      0>(xcx, xcy, xcz, tab, fr[ 0], fr[ 1]);
    enc_linear<21,  10648,   4920>(xcx, xcy, xcz, tab, fr[ 2], fr[ 3]);
    enc_linear<26,  19688,  15568>(xcx, xcy, xcz, tab, fr[ 4], fr[ 5]);
    enc_linear<33,  39304,  35256>(xcx, xcy, xcz, tab, fr[ 6], fr[ 7]);
    enc_linear<41,  74088,  74560>(xcx, xcy, xcz, tab, fr[ 8], fr[ 9]);
    enc_linear<51, 140608, 148648>(xcx, xcy, xcz, tab, fr[10], fr[11]);
    enc_linear<65, 287496, 289256>(xcx, xcy, xcz, tab, fr[12], fr[13]);
    enc_hash< 81,  576752>(xcx, xcy, xcz, tab, fr[14], fr[15]);
    enc_hash<102, 1101040>(xcx, xcy, xcz, tab, fr[16], fr[17]);
    enc_hash<129, 1625328>(xcx, xcy, xcz, tab, fr[18], fr[19]);
    enc_hash<162, 2149616>(xcx, xcy, xcz, tab, fr[20], fr[21]);
    enc_hash<204, 2673904>(xcx, xcy, xcz, tab, fr[22], fr[23]);
    enc_hash<257, 3198192>(xcx, xcy, xcz, tab, fr[24], fr[25]);
    enc_hash<324, 3722480>(xcx, xcy, xcz, tab, fr[26], fr[27]);
    enc_hash<408, 4246768>(xcx, xcy, xcz, tab, fr[28], fr[29]);
    enc_hash<R15, 4771056>(xcx, xcy, xcz, tab, fr[30], fr[31]);

    // ======================= MFMA MLP ======================================
    // Per wave: H^T = W1^T(64x32) @ F^T(32x64); O^T = W2^T(8x64) @ H^T(64x64).
    // k-map used consistently for all A/B packs: (q,e) -> k = 4q+e (e<4),
    // 16+4q+(e-4) (e>=4).  C/D layout (m89-verified): col=lane&15,
    // row=4*(lane>>4)+reg.

    // ---- stage F to LDS as bf16 hi/lo frag-chunks: [plane][q][t] 16B -------
    {
        short8* Fhi = (short8*)wb;              // [qq*64 + t]
        short8* Flo = (short8*)(wb + 4096);
#pragma unroll
        for (int qq = 0; qq < 4; ++qq) {
            short8 vh, vl;
#pragma unroll
            for (int e = 0; e < 8; ++e) {
                const int f = (e < 4) ? (4 * qq + e) : (16 + 4 * qq + (e - 4));
                float x = fr[f];
                short h = bf16_hi(x);
                vh[e] = h;
                vl[e] = bf16_hi(x - bf16_back(h));
            }
            Fhi[qq * 64 + lane] = vh;
            Flo[qq * 64 + lane] = vl;
        }
    }
    asm volatile("s_waitcnt lgkmcnt(0)" ::: "memory");

    // ---- load all 8 F B-frags (then F LDS region is dead) ------------------
    short8 fbh[4], fbl[4];
#pragma unroll
    for (int nt = 0; nt < 4; ++nt) {
        fbh[nt] = *(const short8*)(wb +        (q * 1024 + (16 * nt + cc) * 16));
        fbl[nt] = *(const short8*)(wb + 4096 + (q * 1024 + (16 * nt + cc) * 16));
    }
    asm volatile("s_waitcnt lgkmcnt(0)" ::: "memory");

    const f32x4 zero4 = {0.f, 0.f, 0.f, 0.f};
    f32x4 oacc[4] = {zero4, zero4, zero4, zero4};

#pragma unroll
    for (int kk = 0; kk < 2; ++kk) {
        // ---- layer 1, m-tiles {2kk, 2kk+1} -> hidden rows 32kk..32kk+31 ----
        f32x4 hacc[2][4];
#pragma unroll
        for (int ms = 0; ms < 2; ++ms)
#pragma unroll
            for (int nt = 0; nt < 4; ++nt) hacc[ms][nt] = zero4;

#pragma unroll
        for (int ms = 0; ms < 2; ++ms) {
            const int m = 2 * kk + ms;
            // A-frag of W1^T tile m: lane holds row 16m+cc, k = map(q,e)
            float wv[8];
#pragma unroll
            for (int e = 0; e < 8; ++e) {
                const int f = (e < 4) ? (4 * q + e) : (16 + 4 * q + (e - 4));
                wv[e] = w1[f * 64 + 16 * m + cc];
            }
            short8 ah, al;
#pragma unroll
            for (int e = 0; e < 8; ++e) {
                short h = bf16_hi(wv[e]);
                ah[e] = h;
                al[e] = bf16_hi(wv[e] - bf16_back(h));
            }
#pragma unroll
            for (int nt = 0; nt < 4; ++nt) {
                hacc[ms][nt] = __builtin_amdgcn_mfma_f32_16x16x32_bf16(ah, fbh[nt], hacc[ms][nt], 0, 0, 0);
                hacc[ms][nt] = __builtin_amdgcn_mfma_f32_16x16x32_bf16(ah, fbl[nt], hacc[ms][nt], 0, 0, 0);
                hacc[ms][nt] = __builtin_amdgcn_mfma_f32_16x16x32_bf16(al, fbh[nt], hacc[ms][nt], 0, 0, 0);
            }
        }
        asm volatile("" ::: "memory");

        // ---- relu + split + stage H-half into LDS (overwrites F region) ----
        // hidden 32kk + 16ms + 4q + j  ->  chunk q, col t, element 4ms+j
#pragma unroll
        for (int ms = 0; ms < 2; ++ms) {
#pragma unroll
            for (int nt = 0; nt < 4; ++nt) {
                short4v hh, hl;
#pragma unroll
                for (int j = 0; j < 4; ++j) {
                    float x = fmaxf(hacc[ms][nt][j], 0.f);
                    short h = bf16_hi(x);
                    hh[j] = h;
                    hl[j] = bf16_hi(x - bf16_back(h));
                }
                *(short4v*)(wb +        (q * 1024 + (16 * nt + cc) * 16 + ms * 8)) = hh;
                *(short4v*)(wb + 4096 + (q * 1024 + (16 * nt + cc) * 16 + ms * 8)) = hl;
            }
        }
        asm volatile("s_waitcnt lgkmcnt(0)" ::: "memory");

        // ---- layer 2 A-frag: W2^T, rows = out-dim (valid < 8), k = hidden --
        float wv2[8];
#pragma unroll
        for (int e = 0; e < 8; ++e) {
            const int hi_ = 32 * kk + 16 * (e >> 2) + 4 * q + (e & 3);
            const int cL = cc < 8 ? cc : 7;      // clamp addr, zero below
            float v = w2[hi_ * 8 + cL];
            wv2[e] = (cc < 8) ? v : 0.f;
        }
        short8 a2h, a2l;
#pragma unroll
        for (int e = 0; e < 8; ++e) {
            short h = bf16_hi(wv2[e]);
            a2h[e] = h;
            a2l[e] = bf16_hi(wv2[e] - bf16_back(h));
        }
#pragma unroll
        for (int nt = 0; nt < 4; ++nt) {
            short8 bh = *(const short8*)(wb +        (q * 1024 + (16 * nt + cc) * 16));
            short8 bl = *(const short8*)(wb + 4096 + (q * 1024 + (16 * nt + cc) * 16));
            oacc[nt] = __builtin_amdgcn_mfma_f32_16x16x32_bf16(a2h, bh, oacc[nt], 0, 0, 0);
            oacc[nt] = __builtin_amdgcn_mfma_f32_16x16x32_bf16(a2h, bl, oacc[nt], 0, 0, 0);
            oacc[nt] = __builtin_amdgcn_mfma_f32_16x16x32_bf16(a2l, bh, oacc[nt], 0, 0, 0);
        }
        asm volatile("s_waitcnt lgkmcnt(0)" ::: "memory");
    }

    // ---- O^T (rows=out-j valid<8, cols=wave thread) -> per-thread rows -----
    {
        float* Ob = (float*)wb;                 // [j][t] : j*64 + t
        if (q < 2) {
#pragma unroll
            for (int nt = 0; nt < 4; ++nt)
#pragma unroll
                for (int j = 0; j < 4; ++j)
                    Ob[(4 * q + j) * 64 + 16 * nt + cc] = oacc[nt][j];
        }
        asm volatile("s_waitcnt lgkmcnt(0)" ::: "memory");

        float o[8];
#pragma unroll
        for (int j = 0; j < 8; ++j) o[j] = Ob[j * 64 + lane];

        // ---- outer trilinear weight + 8-lane reduction (unchanged) ---------
        float wt = (ax ? uu : 1.f - uu) * (ay ? vv : 1.f - vv) * (az ? wwf : 1.f - wwf);
#pragma unroll
        for (int j = 0; j < 8; ++j) {
            float v = o[j] * wt;
            v += __shfl_xor(v, 1);
            v += __shfl_xor(v, 2);
            v += __shfl_xor(v, 4);
            o[j] = v;
        }
        float r01 = (a & 1) ? o[1] : o[0];
        float r23 = (a & 1) ? o[3] : o[2];
        float r45 = (a & 1) ? o[5] : o[4];
        float r67 = (a & 1) ? o[7] : o[6];
        float r03 = (a & 2) ? r23 : r01;
        float r47 = (a & 2) ? r67 : r45;
        float r   = (a & 4) ? r47 : r03;
        out[t] = r;
    }
}

extern "C" void kernel_launch(void* const* d_in, const int* in_sizes, int n_in,
                              void* d_out, int out_size, void* d_ws, size_t ws_size,
                              hipStream_t stream) {
    const float* xyz   = (const float*)d_in[0];
    const float* bound = (const float*)d_in[1];
    const float* table = (const float*)d_in[2];
    const float* w1    = (const float*)d_in[3];
    const float* w2    = (const float*)d_in[4];
    float* out = (float*)d_out;

    const int N = in_sizes[0] / 3;          // 262144
    const int threads = N * 8;              // one thread per (point, corner)
    const int blocks = (threads + BLK - 1) / BLK;
    grid_fused<<<blocks, BLK, 0, stream>>>(xyz, bound, table, w1, w2, out, N);
}